// Round 13
// baseline (4687.473 us; speedup 1.0000x reference)
//
#include <hip/hip_runtime.h>
#include <float.h>

// FPS: N=524288 pts, M=2048 selected (idx[0]=0), out = pos[idxs] (2048x3 f32).
// 256 cooperative blocks x 256 threads (1 block/CU, 1 wave/SIMD, PPT=8).
// R9 structure (validated best 4571/4574us: ONLY wave 0 polls fabric, 64B-
// padded value-only slots, one __syncthreads/iter, lane-local-max coord
// prefetch, parallel 3-word LDS relay, no-sleep relay spin) with ONE
// isolated change:
//   2-DEEP PIPELINED POLL, no s_sleep: two sets of 4 slot loads in flight,
//   checked alternately. Sampling period ~380 cyc (was ~765: RT+sleep64),
//   cutting the avg detect-after-visibility wait ~half. Load rate ~1.9x --
//   probes the unprobed gap in the contention map: 1x fine (R4/R9), 4x
//   +34-45% (R6/R7), 2x = THIS. Stale samples are harmless (tags retry).
// Session map: padding is WRITE-side load-bearing (R11 packed +64%); all-
// waves poll +34% (R6); 4x-line poll +45% (R7); dependent multi-word slots
// hurt (R1/R3); s_barrier beats LDS handshakes (R10); compute spread -7%
// (R4); relay trim -1% (R9).

#define NPTS     524288
#define MOUT     2048
#define NBLK     256
#define NTHR     256
#define NWAVE    (NTHR / 64)            // 4
#define GTHREADS (NBLK * NTHR)          // 65536
#define PPT      (NPTS / GTHREADS)      // 8
#define SLOT_STRIDE 8                   // u64 per slot -> one 64 B line/slot
#define MASK51   ((1ull << 51) - 1)

// slot word: [tag:13][fbits:32][idx_inv:19]
// fbits = IEEE bits of min_d (>=0 so bit order == value order)
// idx_inv = (NPTS-1)-idx: equal values -> smaller idx wins the max
// => first-occurrence tie-break == jnp.argmax (absmax 0.0 R0-R12).
// All 256 block bests are globally distinct (point ownership partitioned),
// so every reduce winner is identified by word equality.
// Slot-reuse safety (parity-2 fabric buffers): publish(i+2) requires this
// block's barrier(i+2) <= all its waves passed iter i+1 <= all blocks
// published(i+1) <= their barriers(i+1) <= their wave0 passed poll(i) --
// no word is re-tagged while any poller still wants tag i. Same chain
// covers the parity-2 LDS relay and single-buffer LDS parks (+ barrier).
// Fabric poison 0xAA.. decodes tag 0x1555, never a real tag (1..2047).

#define DPP_MAX_U64(v, ctrl) do {                                            \
    unsigned _lo = (unsigned)__builtin_amdgcn_update_dpp(                    \
        0, (int)(unsigned)(v), (ctrl), 0xf, 0xf, true);                      \
    unsigned _hi = (unsigned)__builtin_amdgcn_update_dpp(                    \
        0, (int)(unsigned)((v) >> 32), (ctrl), 0xf, 0xf, true);              \
    unsigned long long _s = ((unsigned long long)_hi << 32) | _lo;           \
    if (_s > (v)) (v) = _s;                                                  \
} while (0)

__device__ __forceinline__ unsigned long long wave_max_u64(unsigned long long v)
{
    DPP_MAX_U64(v, 0x111);   // row_shr:1
    DPP_MAX_U64(v, 0x112);   // row_shr:2
    DPP_MAX_U64(v, 0x114);   // row_shr:4
    DPP_MAX_U64(v, 0x118);   // row_shr:8   -> lane15 of each row = row max
    DPP_MAX_U64(v, 0x142);   // row_bcast:15
    DPP_MAX_U64(v, 0x143);   // row_bcast:31 -> lane63 = wave max
    unsigned lo = (unsigned)__builtin_amdgcn_readlane((int)(unsigned)v, 63);
    unsigned hi = (unsigned)__builtin_amdgcn_readlane((int)(unsigned)(v >> 32), 63);
    return ((unsigned long long)hi << 32) | lo;
}

__device__ __forceinline__ unsigned long long quad_max_u64(unsigned long long v)
{
    // values replicated every 4 lanes (v = sred[lane&3]); lane3 = max(v0..v3)
    DPP_MAX_U64(v, 0x111);
    DPP_MAX_U64(v, 0x112);
    unsigned lo = (unsigned)__builtin_amdgcn_readlane((int)(unsigned)v, 3);
    unsigned hi = (unsigned)__builtin_amdgcn_readlane((int)(unsigned)(v >> 32), 3);
    return ((unsigned long long)hi << 32) | lo;
}

__device__ __forceinline__ float readlane_f(float v, int l)
{
    return __uint_as_float(
        (unsigned)__builtin_amdgcn_readlane((int)__float_as_uint(v), l));
}

__global__ void __launch_bounds__(NTHR, 1) fps_kernel(
    const float* __restrict__ pos, float* __restrict__ out,
    unsigned long long* __restrict__ slots)
{
    const unsigned tid  = threadIdx.x;
    const unsigned lane = tid & 63u;
    const unsigned wav  = tid >> 6;
    const unsigned blk  = blockIdx.x;
    const unsigned g    = blk * NTHR + tid;

    float X[PPT], Y[PPT], Z[PPT], D[PPT];
#pragma unroll
    for (int p = 0; p < PPT; ++p) {
        const unsigned idx = g + (unsigned)p * GTHREADS;
        X[p] = pos[3u * idx + 0];
        Y[p] = pos[3u * idx + 1];
        Z[p] = pos[3u * idx + 2];
        D[p] = FLT_MAX;
    }

    float px = pos[0], py = pos[1], pz = pos[2];
    if (g == 0) { out[0] = px; out[1] = py; out[2] = pz; }

    // Wave bests (leaders -> wave 0). Single buffer safe: wave w parks i+1
    // only after detecting i via the relay, which wave0 writes only after it
    // already consumed the parks for i (+ the per-iter barrier orders reads).
    __shared__ unsigned long long sred[NWAVE];
    // Parity double-buffered relay (wave 0 -> waves 1-3), self-tagged words.
    __shared__ unsigned long long sbc[2][4];   // words 0..2 used
    if (tid < 8) sbc[tid >> 2][tid & 3] = 0ull;   // tag 0 = invalid
    __syncthreads();

    for (int i = 1; i < MOUT; ++i) {
        // ---- distance update + per-thread argmax (exact fp32: no FMA,
        // ---- sum order (dx^2+dy^2)+dz^2; absmax==0 verified R0-R12) ----
        float bv = -1.0f;
        unsigned bi = 0;
#pragma unroll
        for (int p = 0; p < PPT; ++p) {
            float dx = __fsub_rn(X[p], px);
            float dy = __fsub_rn(Y[p], py);
            float dz = __fsub_rn(Z[p], pz);
            float d  = __fadd_rn(__fadd_rn(__fmul_rn(dx, dx), __fmul_rn(dy, dy)),
                                 __fmul_rn(dz, dz));
            float m  = fminf(D[p], d);
            D[p] = m;
            if (m > bv) { bv = m; bi = g + (unsigned)p * GTHREADS; }
        }
        const unsigned long long mine =
            ((unsigned long long)__float_as_uint(bv) << 19) |
            (unsigned long long)((NPTS - 1u) - bi);

        const unsigned long long tag = (unsigned long long)i;
        const unsigned long long tb  = tag << 51;
        unsigned long long* buf = slots + (unsigned)(i & 1) * (NBLK * SLOT_STRIDE);

        // ---- DPP wave max; leader parks it; barrier orders parks vs read ----
        const unsigned long long wbest = wave_max_u64(mine);
        if (lane == 0) sred[wav] = wbest;
        __syncthreads();

        if (wav == 0) {
            // ---- 4-value DPP reduce -> block best; lane0 publishes ----
            unsigned long long b2 = sred[lane & (NWAVE - 1u)];
            const unsigned long long bbest = quad_max_u64(b2);
            if (lane == 0) {
                __hip_atomic_store(&buf[blk * SLOT_STRIDE], tb | bbest,
                                   __ATOMIC_RELAXED, __HIP_MEMORY_SCOPE_AGENT);
            }

            // ---- 2-deep pipelined poll: two 4-load sets in flight, checked
            // ---- alternately; sampling ~2x faster, no sleep ----
            unsigned long long* base = buf + lane * SLOT_STRIDE;
            unsigned long long s0, s1, s2, s3;
            unsigned long long a0, a1, a2, a3, e0, e1, e2, e3;
#define POLL_LOADS(x0, x1, x2, x3)                                           \
    x0 = __hip_atomic_load(base + 0 * 64 * SLOT_STRIDE,                      \
                           __ATOMIC_RELAXED, __HIP_MEMORY_SCOPE_AGENT);      \
    x1 = __hip_atomic_load(base + 1 * 64 * SLOT_STRIDE,                      \
                           __ATOMIC_RELAXED, __HIP_MEMORY_SCOPE_AGENT);      \
    x2 = __hip_atomic_load(base + 2 * 64 * SLOT_STRIDE,                      \
                           __ATOMIC_RELAXED, __HIP_MEMORY_SCOPE_AGENT);      \
    x3 = __hip_atomic_load(base + 3 * 64 * SLOT_STRIDE,                      \
                           __ATOMIC_RELAXED, __HIP_MEMORY_SCOPE_AGENT)
#define TAGS_OK(x0, x1, x2, x3)                                              \
    (((x0 >> 51) == tag) & ((x1 >> 51) == tag) &                             \
     ((x2 >> 51) == tag) & ((x3 >> 51) == tag))
            POLL_LOADS(a0, a1, a2, a3);
            for (;;) {
                POLL_LOADS(e0, e1, e2, e3);      // set B in flight
                if (TAGS_OK(a0, a1, a2, a3)) {   // waits only on set A
                    s0 = a0; s1 = a1; s2 = a2; s3 = a3; break;
                }
                POLL_LOADS(a0, a1, a2, a3);      // set A back in flight
                if (TAGS_OK(e0, e1, e2, e3)) {   // waits only on set B
                    s0 = e0; s1 = e1; s2 = e2; s3 = e3; break;
                }
            }
#undef POLL_LOADS
#undef TAGS_OK

            // ---- local max of 4 (values globally distinct) ----
            unsigned long long c0 = s0 & MASK51, c1 = s1 & MASK51;
            unsigned long long c2 = s2 & MASK51, c3 = s3 & MASK51;
            unsigned long long ca = (c0 > c1) ? c0 : c1;
            unsigned long long cb = (c2 > c3) ? c2 : c3;
            unsigned long long c  = (ca > cb) ? ca : cb;

            // prefetch this lane's candidate coords; loads fly during reduce
            const unsigned cidx = (NPTS - 1u) - (unsigned)(c & 0x7FFFFull);
            const float cx = pos[3u * cidx + 0];
            const float cy = pos[3u * cidx + 1];
            const float cz = pos[3u * cidx + 2];

            // ---- DPP winner reduce over 64 lane-local maxes; readlane coords ----
            const unsigned long long win = wave_max_u64(c);
            const int src = __ffsll(__ballot(c == win)) - 1;  // unique lane
            px = readlane_f(cx, src);
            py = readlane_f(cy, src);
            pz = readlane_f(cz, src);

            // ---- LDS relay: lanes 0-2 store 3 self-tagged words in parallel ----
            if (lane < 3u) {
                const unsigned cv = (lane == 0u) ? __float_as_uint(px)
                                  : (lane == 1u) ? __float_as_uint(py)
                                                 : __float_as_uint(pz);
                __hip_atomic_store(&sbc[i & 1][lane],
                                   tb | (unsigned long long)cv,
                                   __ATOMIC_RELAXED, __HIP_MEMORY_SCOPE_WORKGROUP);
            }

            if (blk == 0 && lane == 0) {
                out[3 * i + 0] = px; out[3 * i + 1] = py; out[3 * i + 2] = pz;
            }
        } else {
            // ---- waves 1-3: relaxed no-sleep tag-spin on the 3 relay words
            // ---- (own SIMD -> free; each word self-tagged -> no ordering) ----
            unsigned long long xw, yw, zw;
            do {
                xw = __hip_atomic_load(&sbc[i & 1][0],
                                       __ATOMIC_RELAXED, __HIP_MEMORY_SCOPE_WORKGROUP);
                yw = __hip_atomic_load(&sbc[i & 1][1],
                                       __ATOMIC_RELAXED, __HIP_MEMORY_SCOPE_WORKGROUP);
                zw = __hip_atomic_load(&sbc[i & 1][2],
                                       __ATOMIC_RELAXED, __HIP_MEMORY_SCOPE_WORKGROUP);
            } while (!(((xw >> 51) == tag) & ((yw >> 51) == tag) &
                       ((zw >> 51) == tag)));
            px = __uint_as_float((unsigned)xw);
            py = __uint_as_float((unsigned)yw);
            pz = __uint_as_float((unsigned)zw);
        }
        // no trailing sync: next iteration's pre-publish barrier + monotone
        // tags + parity-2 buffers make all reuse safe (chain at top).
    }
}

extern "C" void kernel_launch(void* const* d_in, const int* in_sizes, int n_in,
                              void* d_out, int out_size, void* d_ws, size_t ws_size,
                              hipStream_t stream) {
    const float* pos = (const float*)d_in[0];
    float* out = (float*)d_out;
    unsigned long long* slots = (unsigned long long*)d_ws;  // 2 x 256 x 64B = 32 KB
    // No memset: 0xAA poison decodes to tag 0x1555, never a real tag (1..2047);
    // monotone tags + 2-buffer rotation make stale words harmless.

    void* args[] = { (void*)&pos, (void*)&out, (void*)&slots };
    hipLaunchCooperativeKernel((void*)fps_kernel, dim3(NBLK), dim3(NTHR),
                               args, 0, stream);
}

// Round 14
// 4563.851 us; speedup vs baseline: 1.0271x; 1.0271x over previous
//
#include <hip/hip_runtime.h>
#include <float.h>

// FPS: N=524288 pts, M=2048 selected (idx[0]=0), out = pos[idxs] (2048x3 f32).
// 256 cooperative blocks x 256 threads (1 block/CU, 1 wave/SIMD, PPT=8).
// FINAL (R9, twice-validated best: 4571us R9, 4574us R12): ONLY wave 0
// polls fabric, 4 value-only 64B-padded slot loads/attempt + s_sleep(1),
// one __syncthreads/iter, lane-local-max coord prefetch overlapping the
// winner reduce, parallel 3-word LDS relay, no-sleep relay spin.
//
// Session map (14 rounds) -- every single-change perturbation regresses:
//   polling waves 4x (R6 +34%); poll lines 4x (R7 +45%); packed slots
//   (R11 +64%: padding is WRITE-visibility load-bearing); 2-deep pipelined
//   poll (R13 +2.5%: FETCH flat proved detect exits on ~first sample, so
//   no quantization dead-time exists); LDS handshake for barrier (R10 +4%);
//   dependent multi-word slots (R1/R3 +19-30%); coords-in-slot (all forms
//   worse). Wins banked: compute spread 64->256 CUs (R4 -7%), parallel
//   relay + no-sleep spin (R9 -1%).
// Remaining period = local chain ~1100 cyc + publish visibility + one
// agent-load RT ~2000+ + 256-block straggler skew: a cross-XCD sync-latency
// floor (HBM 0.6%, VALU 22%, zero bank conflicts -- not a resource roofline;
// 2047 serial device-wide argmax rounds at bare coherence latency).

#define NPTS     524288
#define MOUT     2048
#define NBLK     256
#define NTHR     256
#define NWAVE    (NTHR / 64)            // 4
#define GTHREADS (NBLK * NTHR)          // 65536
#define PPT      (NPTS / GTHREADS)      // 8
#define SLOT_STRIDE 8                   // u64 per slot -> one 64 B line/slot
#define MASK51   ((1ull << 51) - 1)

// slot word: [tag:13][fbits:32][idx_inv:19]
// fbits = IEEE bits of min_d (>=0 so bit order == value order)
// idx_inv = (NPTS-1)-idx: equal values -> smaller idx wins the max
// => first-occurrence tie-break == jnp.argmax (absmax 0.0 R0-R13).
// All 256 block bests are globally distinct (point ownership partitioned),
// so every reduce winner is identified by word equality.
// Slot-reuse safety (parity-2 fabric buffers): publish(i+2) requires this
// block's barrier(i+2) <= all its waves passed iter i+1 <= all blocks
// published(i+1) <= their barriers(i+1) <= their wave0 passed poll(i) --
// no word is re-tagged while any poller still wants tag i. Same chain
// covers the parity-2 LDS relay and single-buffer LDS parks (+ barrier).
// Fabric poison 0xAA.. decodes tag 0x1555, never a real tag (1..2047).

#define DPP_MAX_U64(v, ctrl) do {                                            \
    unsigned _lo = (unsigned)__builtin_amdgcn_update_dpp(                    \
        0, (int)(unsigned)(v), (ctrl), 0xf, 0xf, true);                      \
    unsigned _hi = (unsigned)__builtin_amdgcn_update_dpp(                    \
        0, (int)(unsigned)((v) >> 32), (ctrl), 0xf, 0xf, true);              \
    unsigned long long _s = ((unsigned long long)_hi << 32) | _lo;           \
    if (_s > (v)) (v) = _s;                                                  \
} while (0)

__device__ __forceinline__ unsigned long long wave_max_u64(unsigned long long v)
{
    DPP_MAX_U64(v, 0x111);   // row_shr:1
    DPP_MAX_U64(v, 0x112);   // row_shr:2
    DPP_MAX_U64(v, 0x114);   // row_shr:4
    DPP_MAX_U64(v, 0x118);   // row_shr:8   -> lane15 of each row = row max
    DPP_MAX_U64(v, 0x142);   // row_bcast:15
    DPP_MAX_U64(v, 0x143);   // row_bcast:31 -> lane63 = wave max
    unsigned lo = (unsigned)__builtin_amdgcn_readlane((int)(unsigned)v, 63);
    unsigned hi = (unsigned)__builtin_amdgcn_readlane((int)(unsigned)(v >> 32), 63);
    return ((unsigned long long)hi << 32) | lo;
}

__device__ __forceinline__ unsigned long long quad_max_u64(unsigned long long v)
{
    // values replicated every 4 lanes (v = sred[lane&3]); lane3 = max(v0..v3)
    DPP_MAX_U64(v, 0x111);
    DPP_MAX_U64(v, 0x112);
    unsigned lo = (unsigned)__builtin_amdgcn_readlane((int)(unsigned)v, 3);
    unsigned hi = (unsigned)__builtin_amdgcn_readlane((int)(unsigned)(v >> 32), 3);
    return ((unsigned long long)hi << 32) | lo;
}

__device__ __forceinline__ float readlane_f(float v, int l)
{
    return __uint_as_float(
        (unsigned)__builtin_amdgcn_readlane((int)__float_as_uint(v), l));
}

__global__ void __launch_bounds__(NTHR, 1) fps_kernel(
    const float* __restrict__ pos, float* __restrict__ out,
    unsigned long long* __restrict__ slots)
{
    const unsigned tid  = threadIdx.x;
    const unsigned lane = tid & 63u;
    const unsigned wav  = tid >> 6;
    const unsigned blk  = blockIdx.x;
    const unsigned g    = blk * NTHR + tid;

    float X[PPT], Y[PPT], Z[PPT], D[PPT];
#pragma unroll
    for (int p = 0; p < PPT; ++p) {
        const unsigned idx = g + (unsigned)p * GTHREADS;
        X[p] = pos[3u * idx + 0];
        Y[p] = pos[3u * idx + 1];
        Z[p] = pos[3u * idx + 2];
        D[p] = FLT_MAX;
    }

    float px = pos[0], py = pos[1], pz = pos[2];
    if (g == 0) { out[0] = px; out[1] = py; out[2] = pz; }

    // Wave bests (leaders -> wave 0). Single buffer safe: wave w parks i+1
    // only after detecting i via the relay, which wave0 writes only after it
    // already consumed the parks for i (+ the per-iter barrier orders reads).
    __shared__ unsigned long long sred[NWAVE];
    // Parity double-buffered relay (wave 0 -> waves 1-3), self-tagged words.
    __shared__ unsigned long long sbc[2][4];   // words 0..2 used
    if (tid < 8) sbc[tid >> 2][tid & 3] = 0ull;   // tag 0 = invalid
    __syncthreads();

    for (int i = 1; i < MOUT; ++i) {
        // ---- distance update + per-thread argmax (exact fp32: no FMA,
        // ---- sum order (dx^2+dy^2)+dz^2; absmax==0 verified R0-R13) ----
        float bv = -1.0f;
        unsigned bi = 0;
#pragma unroll
        for (int p = 0; p < PPT; ++p) {
            float dx = __fsub_rn(X[p], px);
            float dy = __fsub_rn(Y[p], py);
            float dz = __fsub_rn(Z[p], pz);
            float d  = __fadd_rn(__fadd_rn(__fmul_rn(dx, dx), __fmul_rn(dy, dy)),
                                 __fmul_rn(dz, dz));
            float m  = fminf(D[p], d);
            D[p] = m;
            if (m > bv) { bv = m; bi = g + (unsigned)p * GTHREADS; }
        }
        const unsigned long long mine =
            ((unsigned long long)__float_as_uint(bv) << 19) |
            (unsigned long long)((NPTS - 1u) - bi);

        const unsigned long long tag = (unsigned long long)i;
        const unsigned long long tb  = tag << 51;
        unsigned long long* buf = slots + (unsigned)(i & 1) * (NBLK * SLOT_STRIDE);

        // ---- DPP wave max; leader parks it; barrier orders parks vs read ----
        const unsigned long long wbest = wave_max_u64(mine);
        if (lane == 0) sred[wav] = wbest;
        __syncthreads();

        if (wav == 0) {
            // ---- 4-value DPP reduce -> block best; lane0 publishes ----
            unsigned long long b2 = sred[lane & (NWAVE - 1u)];
            const unsigned long long bbest = quad_max_u64(b2);
            if (lane == 0) {
                __hip_atomic_store(&buf[blk * SLOT_STRIDE], tb | bbest,
                                   __ATOMIC_RELAXED, __HIP_MEMORY_SCOPE_AGENT);
            }

            // ---- poll 256 slots: 4 independent single-word slots/lane ----
            unsigned long long* base = buf + lane * SLOT_STRIDE;
            unsigned long long s0, s1, s2, s3;
            do {
                s0 = __hip_atomic_load(base + 0 * 64 * SLOT_STRIDE,
                                       __ATOMIC_RELAXED, __HIP_MEMORY_SCOPE_AGENT);
                s1 = __hip_atomic_load(base + 1 * 64 * SLOT_STRIDE,
                                       __ATOMIC_RELAXED, __HIP_MEMORY_SCOPE_AGENT);
                s2 = __hip_atomic_load(base + 2 * 64 * SLOT_STRIDE,
                                       __ATOMIC_RELAXED, __HIP_MEMORY_SCOPE_AGENT);
                s3 = __hip_atomic_load(base + 3 * 64 * SLOT_STRIDE,
                                       __ATOMIC_RELAXED, __HIP_MEMORY_SCOPE_AGENT);
                if (((s0 >> 51) == tag) & ((s1 >> 51) == tag) &
                    ((s2 >> 51) == tag) & ((s3 >> 51) == tag)) break;
                __builtin_amdgcn_s_sleep(1);
            } while (true);

            // ---- local max of 4 (values globally distinct) ----
            unsigned long long c0 = s0 & MASK51, c1 = s1 & MASK51;
            unsigned long long c2 = s2 & MASK51, c3 = s3 & MASK51;
            unsigned long long ca = (c0 > c1) ? c0 : c1;
            unsigned long long cb = (c2 > c3) ? c2 : c3;
            unsigned long long c  = (ca > cb) ? ca : cb;

            // prefetch this lane's candidate coords; loads fly during reduce
            const unsigned cidx = (NPTS - 1u) - (unsigned)(c & 0x7FFFFull);
            const float cx = pos[3u * cidx + 0];
            const float cy = pos[3u * cidx + 1];
            const float cz = pos[3u * cidx + 2];

            // ---- DPP winner reduce over 64 lane-local maxes; readlane coords ----
            const unsigned long long win = wave_max_u64(c);
            const int src = __ffsll(__ballot(c == win)) - 1;  // unique lane
            px = readlane_f(cx, src);
            py = readlane_f(cy, src);
            pz = readlane_f(cz, src);

            // ---- LDS relay: lanes 0-2 store 3 self-tagged words in parallel ----
            if (lane < 3u) {
                const unsigned cv = (lane == 0u) ? __float_as_uint(px)
                                  : (lane == 1u) ? __float_as_uint(py)
                                                 : __float_as_uint(pz);
                __hip_atomic_store(&sbc[i & 1][lane],
                                   tb | (unsigned long long)cv,
                                   __ATOMIC_RELAXED, __HIP_MEMORY_SCOPE_WORKGROUP);
            }

            if (blk == 0 && lane == 0) {
                out[3 * i + 0] = px; out[3 * i + 1] = py; out[3 * i + 2] = pz;
            }
        } else {
            // ---- waves 1-3: relaxed no-sleep tag-spin on the 3 relay words
            // ---- (own SIMD -> free; each word self-tagged -> no ordering) ----
            unsigned long long xw, yw, zw;
            do {
                xw = __hip_atomic_load(&sbc[i & 1][0],
                                       __ATOMIC_RELAXED, __HIP_MEMORY_SCOPE_WORKGROUP);
                yw = __hip_atomic_load(&sbc[i & 1][1],
                                       __ATOMIC_RELAXED, __HIP_MEMORY_SCOPE_WORKGROUP);
                zw = __hip_atomic_load(&sbc[i & 1][2],
                                       __ATOMIC_RELAXED, __HIP_MEMORY_SCOPE_WORKGROUP);
            } while (!(((xw >> 51) == tag) & ((yw >> 51) == tag) &
                       ((zw >> 51) == tag)));
            px = __uint_as_float((unsigned)xw);
            py = __uint_as_float((unsigned)yw);
            pz = __uint_as_float((unsigned)zw);
        }
        // no trailing sync: next iteration's pre-publish barrier + monotone
        // tags + parity-2 buffers make all reuse safe (chain at top).
    }
}

extern "C" void kernel_launch(void* const* d_in, const int* in_sizes, int n_in,
                              void* d_out, int out_size, void* d_ws, size_t ws_size,
                              hipStream_t stream) {
    const float* pos = (const float*)d_in[0];
    float* out = (float*)d_out;
    unsigned long long* slots = (unsigned long long*)d_ws;  // 2 x 256 x 64B = 32 KB
    // No memset: 0xAA poison decodes to tag 0x1555, never a real tag (1..2047);
    // monotone tags + 2-buffer rotation make stale words harmless.

    void* args[] = { (void*)&pos, (void*)&out, (void*)&slots };
    hipLaunchCooperativeKernel((void*)fps_kernel, dim3(NBLK), dim3(NTHR),
                               args, 0, stream);
}